// Round 17
// baseline (579.237 us; speedup 1.0000x reference)
//
#include <hip/hip_runtime.h>
#include <hip/hip_bf16.h>
#include <cstddef>
#include <cstdint>

#define BN_EPS 1e-5f

typedef __attribute__((ext_vector_type(8))) _Float16 half8;
typedef __attribute__((ext_vector_type(4))) _Float16 half4;
typedef __attribute__((ext_vector_type(4))) float f32x4;

#define GLOBAL_AS __attribute__((address_space(1)))
#define LDS_AS    __attribute__((address_space(3)))

__device__ __forceinline__ void gload_lds16(const void* g, void* l) {
    __builtin_amdgcn_global_load_lds((const GLOBAL_AS uint32_t*)g,
                                     (LDS_AS uint32_t*)l, 16, 0, 0);
}

__device__ __forceinline__ float sigmoidf_(float x) {
    return 1.f / (1.f + __expf(-x));
}
__device__ __forceinline__ float tanhf_(float x) {
    float e = __expf(2.f * x);
    return 1.f - 2.f / (e + 1.f);
}

// ---------------------------------------------------------------------------
// Block-1 CNN (CI=1): scalar conv3x3 + BN + ReLU + pool (unchanged).
// ---------------------------------------------------------------------------
template <int CI, int OC, int S, int OCB>
__global__ __launch_bounds__(256) void cnn_block1_kernel(
    const float* __restrict__ in, const float* __restrict__ w,
    const float* __restrict__ bias, const float* __restrict__ g,
    const float* __restrict__ be, const float* __restrict__ m,
    const float* __restrict__ v, _Float16* __restrict__ out)
{
    constexpr int PS  = S / 2;
    constexpr int NQ  = (PS * PS) / 256;
    constexpr int NOG = OC / OCB;
    __shared__ float wl[OCB * CI * 9];

    int bid  = blockIdx.x;
    int quad = bid % NQ;
    int t2   = bid / NQ;
    int ocg  = t2 % NOG;
    int img  = t2 / NOG;
    int tid  = threadIdx.x;
    int oc0  = ocg * OCB;

    const float* wsrc = w + (size_t)oc0 * CI * 9;
    for (int i = tid; i < OCB * CI * 9; i += 256) wl[i] = wsrc[i];
    __syncthreads();

    int pp = quad * 256 + tid;
    int pr = pp / PS, pc = pp % PS;
    int r0 = 2 * pr - 1, c0 = 2 * pc - 1;

    int  roff[4], coff[4];
    bool rok[4], cok[4];
#pragma unroll
    for (int i = 0; i < 4; i++) {
        int rr = r0 + i; rok[i] = (rr >= 0 && rr < S); roff[i] = min(max(rr, 0), S - 1) * S;
        int cc = c0 + i; cok[i] = (cc >= 0 && cc < S); coff[i] = min(max(cc, 0), S - 1);
    }

    float acc[OCB][4];
#pragma unroll
    for (int o = 0; o < OCB; o++)
#pragma unroll
        for (int j = 0; j < 4; j++) acc[o][j] = 0.f;

    const float* ip = in + (size_t)img * CI * S * S;
    for (int ci = 0; ci < CI; ++ci) {
        float patch[4][4];
#pragma unroll
        for (int iy = 0; iy < 4; iy++)
#pragma unroll
            for (int ix = 0; ix < 4; ix++) {
                float val = ip[roff[iy] + coff[ix]];
                patch[iy][ix] = (rok[iy] && cok[ix]) ? val : 0.f;
            }
#pragma unroll
        for (int o = 0; o < OCB; o++) {
            const float* wp = wl + ((size_t)o * CI + ci) * 9;
#pragma unroll
            for (int ky = 0; ky < 3; ky++)
#pragma unroll
                for (int kx = 0; kx < 3; kx++) {
                    float ww = wp[ky * 3 + kx];
                    acc[o][0] += ww * patch[ky][kx];
                    acc[o][1] += ww * patch[ky][kx + 1];
                    acc[o][2] += ww * patch[ky + 1][kx];
                    acc[o][3] += ww * patch[ky + 1][kx + 1];
                }
        }
        ip += S * S;
    }

    half8 hv;
#pragma unroll
    for (int o = 0; o < OCB; o++) {
        int oc = oc0 + o;
        float scale = g[oc] * rsqrtf(v[oc] + BN_EPS);
        float shift = be[oc] - m[oc] * scale + bias[oc] * scale;
        float r00 = fmaxf(acc[o][0] * scale + shift, 0.f);
        float r01 = fmaxf(acc[o][1] * scale + shift, 0.f);
        float r10 = fmaxf(acc[o][2] * scale + shift, 0.f);
        float r11 = fmaxf(acc[o][3] * scale + shift, 0.f);
        hv[o] = (_Float16)fmaxf(fmaxf(r00, r01), fmaxf(r10, r11));
    }
    *(half8*)(&out[((size_t)img * (PS * PS) + pp) * OC + oc0]) = hv;
}

// ---------------------------------------------------------------------------
// Conv weight prep (unchanged).
// ---------------------------------------------------------------------------
template <int OC, int CI>
__global__ __launch_bounds__(256) void wprep_conv_kernel(
    const float* __restrict__ W, _Float16* __restrict__ Wc)
{
    constexpr int K  = CI * 9;
    constexpr int CH = K / 8;
    int idx = blockIdx.x * 256 + threadIdx.x;
    if (idx >= OC * CH) return;
    int oc = idx / CH, chunk = idx % CH;
    int k0   = chunk * 8;
    int kcp  = (k0 >> 3) & 3;
    int kcl  = kcp ^ ((oc >> 1) & 3);
    int klog = (k0 & ~31) | (kcl << 3);
    int tap = klog / CI, ci = klog % CI;
    const float* src = W + ((size_t)oc * CI + ci) * 9 + tap;
    _Float16* dst = Wc + (size_t)oc * K + k0;
#pragma unroll
    for (int j = 0; j < 8; ++j) dst[j] = (_Float16)src[(size_t)j * 9];
}

// ---------------------------------------------------------------------------
// LSTM weight prep, BOTH layers in one launch (block range selects layer).
// ---------------------------------------------------------------------------
__global__ __launch_bounds__(256) void wprep2_kernel(
    const float* __restrict__ W0, _Float16* __restrict__ Wp0o,
    const float* __restrict__ W1, _Float16* __restrict__ Wp1o)
{
    int gidx = blockIdx.x * 256 + threadIdx.x;   // 0 .. 2*1024*576-1
    const float* W = (gidx < 589824) ? W0 : W1;
    _Float16* Wp   = (gidx < 589824) ? Wp0o : Wp1o;
    int idx = (gidx < 589824) ? gidx : (gidx - 589824);
    int row   = idx / 576;
    int chunk = idx % 576;
    int k0    = chunk * 8;
    int kcell = k0 >> 5;
    int kcp   = (k0 >> 3) & 3;
    int kcl   = kcp ^ ((row >> 1) & 3);
    int klog  = kcell * 32 + kcl * 8;
    int c = row >> 2, ggate = row & 3;
    int zc = ggate * 256 + c;
    int part = (klog >= 2304) ? 1 : 0;
    int rem  = klog - part * 2304;
    int tap  = rem >> 8;
    int ci   = rem & 255;
    const float* src = W + (size_t)zc * 4608 + (size_t)(part * 256 + ci) * 9 + tap;
    _Float16* dst = Wp + (size_t)row * 4608 + k0;
#pragma unroll
    for (int j = 0; j < 8; ++j) dst[j] = (_Float16)src[(size_t)j * 9];
}

// ---------------------------------------------------------------------------
// MFMA implicit-GEMM conv3x3 + BN + ReLU + pool2x2 (blocks 2 and 3).
// 64x64 tile, 4 waves (wave = 16 M rows x 64 N px: 1 A-frag, 4 B-frags).
// PAIRED K-steps, 6 LDS buffers (48KB -> 3 blocks/CU), uniform staging
// (2 A + 2 B gloads per thread per pair, single vmcnt(4) path).
// ---------------------------------------------------------------------------
template <int CI, int OC, int SIN>
__global__ __launch_bounds__(256, 3) void conv_mfma_kernel(
    const _Float16* __restrict__ Wc, const _Float16* __restrict__ in,
    const float* __restrict__ bias, const float* __restrict__ g,
    const float* __restrict__ be, const float* __restrict__ m,
    const float* __restrict__ v, const _Float16* __restrict__ zpage,
    _Float16* __restrict__ out)
{
    constexpr int K    = CI * 9;
    constexpr int KS   = K / 32;
    constexpr int NP   = KS / 2;
    constexpr int SPT  = CI / 32;        // 2 or 4: pairs always share a tap
    constexpr int NPX  = SIN * SIN;
    constexpr int POOL = SIN / 2;
    constexpr int NPP  = NPX / 4;
    constexpr int MB     = OC / 64;
    constexpr int NT     = (32 * NPX) / 64;
    constexpr int NCHUNK = NT / 8;

    __shared__ _Float16 Al[6][2048];   // 64 rows x 32 k (4KB each)
    __shared__ _Float16 Bl[6][2048];   // 64 px  x 32 k (4KB each)

    const int tid = threadIdx.x;
    const int gx   = blockIdx.x & 7;
    const int rest = blockIdx.x >> 3;
    const int nb   = gx * NCHUNK + (rest % NCHUNK);
    const int bm   = rest / NCHUNK;

    const int n0  = nb * 64;
    const int img = n0 / NPX;
    const int r   = n0 - img * NPX;

    const int srow = tid >> 2;              // 0..63
    const int kc   = tid & 3;
    const int kcs  = kc ^ ((srow >> 1) & 3);
    const int wid  = tid >> 6;

    const _Float16* aptr = Wc + (size_t)(bm * 64 + srow) * K + kc * 8;

    const int rn   = r + srow;
    const int ppix = rn >> 2, quad = rn & 3;
    const int y = (ppix / POOL) * 2 + (quad >> 1);
    const int x = (ppix % POOL) * 2 + (quad & 1);
    const _Float16* imgbase = in + (size_t)img * NPX * CI;

    const int lane = tid & 63;
    const int kq   = lane >> 4;
    const int acol = lane & 15;
    const int arow = wid * 16 + acol;
    const int a_off = arow * 64 + ((kq ^ ((arow >> 1) & 3)) << 4);
    int b_off[4];
#pragma unroll
    for (int nf = 0; nf < 4; nf++) {
        int brow = nf * 16 + acol;
        b_off[nf] = brow * 64 + ((kq ^ ((brow >> 1) & 3)) << 4);
    }

    f32x4 acc[4];
#pragma unroll
    for (int nf = 0; nf < 4; nf++) acc[nf] = {0.f, 0.f, 0.f, 0.f};

    // stage K-steps sp, sp+1 (same conv tap) into buffers b2, b2+1
    auto stage_pair = [&](int sp, int b2) {
        gload_lds16(aptr + (size_t)sp * 32,       (char*)&Al[b2][0]     + wid * 1024);
        gload_lds16(aptr + (size_t)(sp + 1) * 32, (char*)&Al[b2 + 1][0] + wid * 1024);
        int tap = sp / SPT;
        int ci0 = (sp % SPT) * 32;
        int dy = tap / 3 - 1, dx = tap - (tap / 3) * 3 - 1;
        int yy = y + dy, xx = x + dx;
        bool ok = (yy >= 0) && (yy < SIN) && (xx >= 0) && (xx < SIN);
        const _Float16* base = ok ? (imgbase + (size_t)(yy * SIN + xx) * CI) : zpage;
        const _Float16* p0 = base + ci0 + kcs * 8;
        gload_lds16(p0,      (char*)&Bl[b2][0]     + wid * 1024);
        gload_lds16(p0 + 32, (char*)&Bl[b2 + 1][0] + wid * 1024);
    };

    stage_pair(0, 0);
    stage_pair(2, 2);

    int cb = 0, ib = 4;
    for (int p = 0; p < NP; ++p) {
        __builtin_amdgcn_sched_barrier(0);
        if (p < NP - 1) asm volatile("s_waitcnt vmcnt(4)" ::: "memory");
        else            asm volatile("s_waitcnt vmcnt(0)" ::: "memory");
        __builtin_amdgcn_s_barrier();
        int sp = 2 * p + 4;
        if (sp < KS) stage_pair(sp, ib);

#pragma unroll
        for (int hs = 0; hs < 2; ++hs) {
            const int bb = cb + hs;
            half8 af = *(const half8*)((const char*)&Al[bb][0] + a_off);
#pragma unroll
            for (int nf = 0; nf < 4; nf++) {
                half8 bf = *(const half8*)((const char*)&Bl[bb][0] + b_off[nf]);
                acc[nf] = __builtin_amdgcn_mfma_f32_16x16x32_f16(af, bf, acc[nf], 0, 0, 0);
            }
        }

        cb = (cb == 4) ? 0 : cb + 2;
        ib = (ib == 4) ? 0 : ib + 2;
    }

    // ---- epilogue: BN + ReLU + pool(4 adjacent N cols) + half4 store ----
    const int oc0w = bm * 64 + wid * 16 + kq * 4;
    float sc[4], sh[4];
#pragma unroll
    for (int j = 0; j < 4; j++) {
        int oc = oc0w + j;
        sc[j] = g[oc] * rsqrtf(v[oc] + BN_EPS);
        sh[j] = be[oc] - m[oc] * sc[j] + bias[oc] * sc[j];
    }
#pragma unroll
    for (int nf = 0; nf < 4; nf++) {
        f32x4 a = acc[nf];
        half4 hv;
#pragma unroll
        for (int j = 0; j < 4; j++) {
            float val = fmaxf(a[j] * sc[j] + sh[j], 0.f);
            val = fmaxf(val, __shfl_xor(val, 1));
            val = fmaxf(val, __shfl_xor(val, 2));
            hv[j] = (_Float16)val;
        }
        if ((acol & 3) == 0) {
            int pl = (r + nf * 16 + acol) >> 2;
            *(half4*)(&out[((size_t)img * NPP + pl) * OC + oc0w]) = hv;
        }
    }
}

// ---------------------------------------------------------------------------
// Serial-loop kernel (r14-verified BEST config): 64x32 tile, 256 threads =
// 4 waves, PAIRED K-steps, one barrier + vmcnt per 2 steps, 6 LDS buffers
// (36KB -> 4 blocks/CU). Waves 0-1 stage B, waves 2-3 A only. UNCHANGED.
// ---------------------------------------------------------------------------
struct Seg {
    const _Float16* W;       // row base (x-part: Wp; h-part: Wp + 2304)
    const float* lbias;
    const _Float16* hsrc; long hs;   // conv input image [px][ch]
    _Float16* zx;  long zxs;         // gate quads: in (mode 0) / out (mode 1)
    float* cstate;
    _Float16* hdst; long hds;
    float* outseq; long osb;
    float* outlast;
    int mode;
};

__global__ __launch_bounds__(256, 4) void lstm3_kernel(
    Seg s0, Seg s1, Seg s2, Seg s3, int e0, int e1, int e2,
    const _Float16* __restrict__ zpage)
{
    __shared__ _Float16 Al[6][2048];   // 64 rows x 32 k (4KB each)
    __shared__ _Float16 Bl[6][1024];   // 32 px  x 32 k (2KB each)

    const int b = blockIdx.x;
    Seg S; int i;
    if (b < e0)      { S = s0; i = b; }
    else if (b < e1) { S = s1; i = b - e0; }
    else if (b < e2) { S = s2; i = b - e1; }
    else             { S = s3; i = b - e2; }

    const int tid = threadIdx.x;
    const int bm  = (i & 7) | (((i >> 3) & 1) << 3);   // 0..15, low3 XCD-stable
    const int nn  = i >> 4;                            // 0..15
    const int img = nn >> 3;
    const int px0 = (nn & 7) * 32;

    const int wid  = tid >> 6;
    const int lane = tid & 63;
    const int lrow = lane >> 2;           // 0..15
    const int kc   = lane & 3;
    const int rowt = wid * 16 + lrow;     // tile row (A stage) / tile pixel (B, wid<2)
    const int kcs  = kc ^ ((rowt >> 1) & 3);

    const _Float16* aptr = S.W + (size_t)(bm * 64 + rowt) * 4608 + kc * 8;

    const int p_pix = px0 + rowt;         // valid for wid<2 (B staging)
    const int py = p_pix >> 4, px = p_pix & 15;

    const _Float16* srcH = S.hsrc + (size_t)img * S.hs;

    const int kq   = lane >> 4;
    const int acol = lane & 15;
    const int arow = wid * 16 + acol;
    const int a_off  = arow * 64 + ((kq ^ ((arow >> 1) & 3)) << 4);
    const int b_off0 = acol * 64 + ((kq ^ ((acol >> 1) & 3)) << 4);
    const int brow1  = 16 + acol;
    const int b_off1 = brow1 * 64 + ((kq ^ ((brow1 >> 1) & 3)) << 4);

    f32x4 acc0 = {0.f, 0.f, 0.f, 0.f};
    f32x4 acc1 = {0.f, 0.f, 0.f, 0.f};

    const int NPAIR = 36;   // 72 K-steps / 2

    // issue stages s2 and s2+1 (always the same conv tap) into bufs b2, b2+1
    auto stage_pair = [&](int sp, int b2) {
        gload_lds16(aptr + (size_t)sp * 32,       (char*)&Al[b2][0]     + wid * 1024);
        gload_lds16(aptr + (size_t)(sp + 1) * 32, (char*)&Al[b2 + 1][0] + wid * 1024);
        if (wid < 2) {
            int tap = sp >> 3;
            int cc  = sp & 7;
            int t3  = tap / 3;
            int dy = t3 - 1, dx = tap - t3 * 3 - 1;
            int yy = py + dy, xx = px + dx;
            bool ok = (yy >= 0) && (yy < 16) && (xx >= 0) && (xx < 16);
            const _Float16* bsrc = ok ? (srcH + (size_t)(yy * 16 + xx) * 256) : zpage;
            const _Float16* p0 = bsrc + cc * 32 + kcs * 8;
            gload_lds16(p0,      (char*)&Bl[b2][0]     + wid * 1024);
            gload_lds16(p0 + 32, (char*)&Bl[b2 + 1][0] + wid * 1024);
        }
    };

    stage_pair(0, 0);
    stage_pair(2, 2);

    int cb = 0;   // buffer of even consumed step
    int ib = 4;   // buffer of even issued stage
    for (int p = 0; p < NPAIR; ++p) {
        __builtin_amdgcn_sched_barrier(0);
        if (wid < 2) {
            if (p < NPAIR - 1) asm volatile("s_waitcnt vmcnt(4)" ::: "memory");
            else               asm volatile("s_waitcnt vmcnt(0)" ::: "memory");
        } else {
            if (p < NPAIR - 1) asm volatile("s_waitcnt vmcnt(2)" ::: "memory");
            else               asm volatile("s_waitcnt vmcnt(0)" ::: "memory");
        }
        __builtin_amdgcn_s_barrier();
        int sp = 2 * p + 4;
        if (sp < 72) stage_pair(sp, ib);

        // step 2p (buf cb)
        {
            half8 af  = *(const half8*)((const char*)&Al[cb][0] + a_off);
            half8 bf0 = *(const half8*)((const char*)&Bl[cb][0] + b_off0);
            half8 bf1 = *(const half8*)((const char*)&Bl[cb][0] + b_off1);
            acc0 = __builtin_amdgcn_mfma_f32_16x16x32_f16(af, bf0, acc0, 0, 0, 0);
            acc1 = __builtin_amdgcn_mfma_f32_16x16x32_f16(af, bf1, acc1, 0, 0, 0);
        }
        // step 2p+1 (buf cb+1)
        {
            half8 af  = *(const half8*)((const char*)&Al[cb + 1][0] + a_off);
            half8 bf0 = *(const half8*)((const char*)&Bl[cb + 1][0] + b_off0);
            half8 bf1 = *(const half8*)((const char*)&Bl[cb + 1][0] + b_off1);
            acc0 = __builtin_amdgcn_mfma_f32_16x16x32_f16(af, bf0, acc0, 0, 0, 0);
            acc1 = __builtin_amdgcn_mfma_f32_16x16x32_f16(af, bf1, acc1, 0, 0, 0);
        }

        cb = (cb == 4) ? 0 : cb + 2;
        ib = (ib == 4) ? 0 : ib + 2;
    }

    const int c = bm * 16 + wid * 4 + kq;

    if (S.mode == 1) {
        // x-conv GEMM: write gate quads
#pragma unroll
        for (int cN = 0; cN < 2; ++cN) {
            f32x4 a = cN ? acc1 : acc0;
            int pxg = px0 + cN * 16 + acol;
            half4 hv;
#pragma unroll
            for (int j = 0; j < 4; j++) hv[j] = (_Float16)a[j];
            *(half4*)(&S.zx[(size_t)img * S.zxs + ((size_t)c * 256 + pxg) * 4]) = hv;
        }
        return;
    }

    // ---- cell epilogue: z = acc + zx + bias ----
    float bi  = S.lbias[c];
    float bf_ = S.lbias[256 + c];
    float bo  = S.lbias[512 + c];
    float bg  = S.lbias[768 + c];

#pragma unroll
    for (int cN = 0; cN < 2; ++cN) {
        f32x4 a = cN ? acc1 : acc0;
        int pxg = px0 + cN * 16 + acol;
        half4 zv = *(const half4*)(&S.zx[(size_t)img * S.zxs + ((size_t)c * 256 + pxg) * 4]);
        size_t off = (size_t)img * 65536 + (size_t)c * 256 + pxg;
        float zi = a[0] + (float)zv[0] + bi;
        float zf = a[1] + (float)zv[1] + bf_;
        float zo = a[2] + (float)zv[2] + bo;
        float zg = a[3] + (float)zv[3] + bg;
        float cold = S.cstate[off];
        float cn = sigmoidf_(zf) * cold + sigmoidf_(zi) * tanhf_(zg);
        float hn = sigmoidf_(zo) * tanhf_(cn);
        S.cstate[off] = cn;
        S.hdst[(size_t)img * S.hds + (size_t)pxg * 256 + c] = (_Float16)hn;
        if (S.outseq) {
            S.outseq[(size_t)img * S.osb + (size_t)c * 256 + pxg] = hn;
            if (S.outlast)
                S.outlast[(size_t)img * 65536 + (size_t)c * 256 + pxg] = hn;
        }
    }
}

// ---------------------------------------------------------------------------
extern "C" void kernel_launch(void* const* d_in, const int* in_sizes, int n_in,
                              void* d_out, int out_size, void* d_ws, size_t ws_size,
                              hipStream_t stream)
{
    const float* x   = (const float*)d_in[0];
    const float* w0  = (const float*)d_in[1];
    const float* b0  = (const float*)d_in[2];
    const float* g0  = (const float*)d_in[3];
    const float* be0 = (const float*)d_in[4];
    const float* m0  = (const float*)d_in[5];
    const float* v0  = (const float*)d_in[6];
    const float* w1  = (const float*)d_in[7];
    const float* b1  = (const float*)d_in[8];
    const float* g1  = (const float*)d_in[9];
    const float* be1 = (const float*)d_in[10];
    const float* m1  = (const float*)d_in[11];
    const float* v1  = (const float*)d_in[12];
    const float* w2  = (const float*)d_in[13];
    const float* b2  = (const float*)d_in[14];
    const float* g2  = (const float*)d_in[15];
    const float* be2 = (const float*)d_in[16];
    const float* m2  = (const float*)d_in[17];
    const float* v2  = (const float*)d_in[18];
    const float* lw0 = (const float*)d_in[19];
    const float* lb0 = (const float*)d_in[20];
    const float* lw1 = (const float*)d_in[21];
    const float* lb1 = (const float*)d_in[22];

    float* out = (float*)d_out;   // fp32 output

    // ---- workspace layout (bytes), peak ~48.3 MiB ----
    char* base = (char*)d_ws;
    _Float16* Wp0  = (_Float16*)(base);                // [0, 9437184)
    _Float16* Wp1  = (_Float16*)(base + 9437184);      // [9437184, 18874368)
    _Float16* h0s  = (_Float16*)(base + 18874368);     // 4 MiB
    _Float16* y2h  = (_Float16*)(base + 25165824);     // 4 MiB
    _Float16* Wc2  = (_Float16*)(base + 29360128);     // 147,456
    _Float16* Wc3  = (_Float16*)(base + 29507584);     // 589,824
    _Float16* zpg  = (_Float16*)(base + 30097408);     // 131,072
    _Float16* hb1a = (_Float16*)(base + 30228480);     // 262,144
    _Float16* hb1b = (_Float16*)(base + 30490624);     // 262,144
    float*    cst0 = (float*)(base + 30752768);        // 524,288
    float*    cst1 = (float*)(base + 31277056);        // 524,288
    _Float16* zx1a = (_Float16*)(base + 31801344);     // 1,048,576
    _Float16* zx1b = (_Float16*)(base + 32849920);     // 1,048,576
    _Float16* zx0  = (_Float16*)(base + 33898496);     // 16,777,216
    // CNN-phase-only regions (time-disjoint):
    _Float16* y0   = (_Float16*)(base);                // [0, 16777216)
    _Float16* y1   = (_Float16*)(base + 16777216);     // [16777216, 25165824)

    // one memset clears zpg + hb1a/b (written before read) + cst0 + cst1
    hipMemsetAsync(zpg, 0, (size_t)(31801344 - 30097408), stream);

    // ---- CNN encoder ----
    cnn_block1_kernel<1, 64, 128, 8><<<32 * 8 * 16, 256, 0, stream>>>(
        x, w0, b0, g0, be0, m0, v0, y0);
    wprep_conv_kernel<128, 64><<<36, 256, 0, stream>>>(w1, Wc2);
    conv_mfma_kernel<64, 128, 64><<<4096, 256, 0, stream>>>(
        Wc2, y0, b1, g1, be1, m1, v1, zpg, y1);
    wprep_conv_kernel<256, 128><<<144, 256, 0, stream>>>(w2, Wc3);
    conv_mfma_kernel<128, 256, 32><<<2048, 256, 0, stream>>>(
        Wc3, y1, b2, g2, be2, m2, v2, zpg, y2h);

    // ---- LSTM weight prep, both layers in one launch (y0/y1 dead now) ----
    wprep2_kernel<<<4608, 256, 0, stream>>>(lw0, Wp0, lw1, Wp1);

    const long IS = 16 * 65536;

    auto makeD = [&](int t) {
        Seg D{};
        D.W = Wp0; D.lbias = lb0;
        D.hsrc = y2h + (size_t)t * 65536; D.hs = IS;
        D.zx = zx0 + (size_t)t * 262144; D.zxs = 16 * 262144;
        D.cstate = nullptr; D.hdst = nullptr; D.hds = 0;
        D.outseq = nullptr; D.osb = 0; D.outlast = nullptr; D.mode = 1;
        return D;
    };

    // ---- pre-loop: zx0 for t=0,1 (A[0] and A[1] consume them) ----
    {
        Seg D0 = makeD(0), D1 = makeD(1);
        lstm3_kernel<<<512, 256, 0, stream>>>(D0, D1, D1, D1, 256, 512, 512, zpg);
    }

    // ---- serial pipeline: dispatch d = {A:L0[d], C:zx1[d-1], B:L1[d-2], D:zx0[d+2]} ----
    for (int d = 0; d <= 17; ++d) {
        const bool doA = (d <= 15);
        const bool doC = (d >= 1 && d <= 16);
        const bool doB = (d >= 2);
        const bool doD = (d <= 13);

        Seg segs[4]; int ns = 0; int cum = 0; int ends[4];
        if (doA) {
            int t = d;
            Seg A{};
            A.W = Wp0 + 2304; A.lbias = lb0;
            A.hsrc = (t == 0) ? zpg : (h0s + (size_t)(t - 1) * 65536);
            A.hs   = (t == 0) ? 0 : IS;
            A.zx = zx0 + (size_t)t * 262144; A.zxs = 16 * 262144;
            A.cstate = cst0;
            A.hdst = h0s + (size_t)t * 65536; A.hds = IS;
            A.outseq = nullptr; A.osb = 0; A.outlast = nullptr; A.mode = 0;
            segs[ns] = A; cum += 256; ends[ns++] = cum;
        }
        if (doC) {
            int u = d - 1;
            Seg C{};
            C.W = Wp1; C.lbias = lb1;
            C.hsrc = h0s + (size_t)u * 65536; C.hs = IS;
            C.zx = (u & 1) ? zx1b : zx1a; C.zxs = 262144;
            C.cstate = nullptr; C.hdst = nullptr; C.hds = 0;
            C.outseq = nullptr; C.osb = 0; C.outlast = nullptr; C.mode = 1;
            segs[ns] = C; cum += 256; ends[ns++] = cum;
        }
        if (doB) {
            int v = d - 2;
            Seg B{};
            B.W = Wp1 + 2304; B.lbias = lb1;
            B.hsrc = (v == 0) ? zpg : ((v & 1) ? hb1a : hb1b);
            B.hs   = (v == 0) ? 0 : 65536;
            B.zx = (v & 1) ? zx1b : zx1a; B.zxs = 262144;
            B.cstate = cst1;
            B.hdst = (v & 1) ? hb1b : hb1a; B.hds = 65536;
            B.outseq = out + (size_t)v * 65536; B.osb = 1048576;
            B.outlast = (v == 15) ? (out + 2097152) : nullptr; B.mode = 0;
            segs[ns] = B; cum += 256; ends[ns++] = cum;
        }
        if (doD) {
            segs[ns] = makeD(d + 2); cum += 256; ends[ns++] = cum;
        }
        for (int k = ns; k < 4; ++k) segs[k] = segs[0];
        int e0 = ends[0];
        int e1 = (ns > 1) ? ends[1] : cum;
        int e2 = (ns > 2) ? ends[2] : cum;
        lstm3_kernel<<<cum, 256, 0, stream>>>(
            segs[0], segs[1], segs[2], segs[3], e0, e1, e2, zpg);
    }
}

// Round 18
// 570.219 us; speedup vs baseline: 1.0158x; 1.0158x over previous
//
#include <hip/hip_runtime.h>
#include <hip/hip_bf16.h>
#include <cstddef>
#include <cstdint>

#define BN_EPS 1e-5f

typedef __attribute__((ext_vector_type(8))) _Float16 half8;
typedef __attribute__((ext_vector_type(4))) _Float16 half4;
typedef __attribute__((ext_vector_type(4))) float f32x4;

#define GLOBAL_AS __attribute__((address_space(1)))
#define LDS_AS    __attribute__((address_space(3)))

__device__ __forceinline__ void gload_lds16(const void* g, void* l) {
    __builtin_amdgcn_global_load_lds((const GLOBAL_AS uint32_t*)g,
                                     (LDS_AS uint32_t*)l, 16, 0, 0);
}

__device__ __forceinline__ float sigmoidf_(float x) {
    return 1.f / (1.f + __expf(-x));
}
__device__ __forceinline__ float tanhf_(float x) {
    float e = __expf(2.f * x);
    return 1.f - 2.f / (e + 1.f);
}

// ---------------------------------------------------------------------------
// Block-1 CNN (CI=1): scalar conv3x3 + BN + ReLU + pool (unchanged).
// ---------------------------------------------------------------------------
template <int CI, int OC, int S, int OCB>
__global__ __launch_bounds__(256) void cnn_block1_kernel(
    const float* __restrict__ in, const float* __restrict__ w,
    const float* __restrict__ bias, const float* __restrict__ g,
    const float* __restrict__ be, const float* __restrict__ m,
    const float* __restrict__ v, _Float16* __restrict__ out)
{
    constexpr int PS  = S / 2;
    constexpr int NQ  = (PS * PS) / 256;
    constexpr int NOG = OC / OCB;
    __shared__ float wl[OCB * CI * 9];

    int bid  = blockIdx.x;
    int quad = bid % NQ;
    int t2   = bid / NQ;
    int ocg  = t2 % NOG;
    int img  = t2 / NOG;
    int tid  = threadIdx.x;
    int oc0  = ocg * OCB;

    const float* wsrc = w + (size_t)oc0 * CI * 9;
    for (int i = tid; i < OCB * CI * 9; i += 256) wl[i] = wsrc[i];
    __syncthreads();

    int pp = quad * 256 + tid;
    int pr = pp / PS, pc = pp % PS;
    int r0 = 2 * pr - 1, c0 = 2 * pc - 1;

    int  roff[4], coff[4];
    bool rok[4], cok[4];
#pragma unroll
    for (int i = 0; i < 4; i++) {
        int rr = r0 + i; rok[i] = (rr >= 0 && rr < S); roff[i] = min(max(rr, 0), S - 1) * S;
        int cc = c0 + i; cok[i] = (cc >= 0 && cc < S); coff[i] = min(max(cc, 0), S - 1);
    }

    float acc[OCB][4];
#pragma unroll
    for (int o = 0; o < OCB; o++)
#pragma unroll
        for (int j = 0; j < 4; j++) acc[o][j] = 0.f;

    const float* ip = in + (size_t)img * CI * S * S;
    for (int ci = 0; ci < CI; ++ci) {
        float patch[4][4];
#pragma unroll
        for (int iy = 0; iy < 4; iy++)
#pragma unroll
            for (int ix = 0; ix < 4; ix++) {
                float val = ip[roff[iy] + coff[ix]];
                patch[iy][ix] = (rok[iy] && cok[ix]) ? val : 0.f;
            }
#pragma unroll
        for (int o = 0; o < OCB; o++) {
            const float* wp = wl + ((size_t)o * CI + ci) * 9;
#pragma unroll
            for (int ky = 0; ky < 3; ky++)
#pragma unroll
                for (int kx = 0; kx < 3; kx++) {
                    float ww = wp[ky * 3 + kx];
                    acc[o][0] += ww * patch[ky][kx];
                    acc[o][1] += ww * patch[ky][kx + 1];
                    acc[o][2] += ww * patch[ky + 1][kx];
                    acc[o][3] += ww * patch[ky + 1][kx + 1];
                }
        }
        ip += S * S;
    }

    half8 hv;
#pragma unroll
    for (int o = 0; o < OCB; o++) {
        int oc = oc0 + o;
        float scale = g[oc] * rsqrtf(v[oc] + BN_EPS);
        float shift = be[oc] - m[oc] * scale + bias[oc] * scale;
        float r00 = fmaxf(acc[o][0] * scale + shift, 0.f);
        float r01 = fmaxf(acc[o][1] * scale + shift, 0.f);
        float r10 = fmaxf(acc[o][2] * scale + shift, 0.f);
        float r11 = fmaxf(acc[o][3] * scale + shift, 0.f);
        hv[o] = (_Float16)fmaxf(fmaxf(r00, r01), fmaxf(r10, r11));
    }
    *(half8*)(&out[((size_t)img * (PS * PS) + pp) * OC + oc0]) = hv;
}

// ---------------------------------------------------------------------------
// Conv weight prep (unchanged).
// ---------------------------------------------------------------------------
template <int OC, int CI>
__global__ __launch_bounds__(256) void wprep_conv_kernel(
    const float* __restrict__ W, _Float16* __restrict__ Wc)
{
    constexpr int K  = CI * 9;
    constexpr int CH = K / 8;
    int idx = blockIdx.x * 256 + threadIdx.x;
    if (idx >= OC * CH) return;
    int oc = idx / CH, chunk = idx % CH;
    int k0   = chunk * 8;
    int kcp  = (k0 >> 3) & 3;
    int kcl  = kcp ^ ((oc >> 1) & 3);
    int klog = (k0 & ~31) | (kcl << 3);
    int tap = klog / CI, ci = klog % CI;
    const float* src = W + ((size_t)oc * CI + ci) * 9 + tap;
    _Float16* dst = Wc + (size_t)oc * K + k0;
#pragma unroll
    for (int j = 0; j < 8; ++j) dst[j] = (_Float16)src[(size_t)j * 9];
}

// ---------------------------------------------------------------------------
// LSTM weight prep, BOTH layers in one launch (block range selects layer).
// ---------------------------------------------------------------------------
__global__ __launch_bounds__(256) void wprep2_kernel(
    const float* __restrict__ W0, _Float16* __restrict__ Wp0o,
    const float* __restrict__ W1, _Float16* __restrict__ Wp1o)
{
    int gidx = blockIdx.x * 256 + threadIdx.x;   // 0 .. 2*1024*576-1
    const float* W = (gidx < 589824) ? W0 : W1;
    _Float16* Wp   = (gidx < 589824) ? Wp0o : Wp1o;
    int idx = (gidx < 589824) ? gidx : (gidx - 589824);
    int row   = idx / 576;
    int chunk = idx % 576;
    int k0    = chunk * 8;
    int kcell = k0 >> 5;
    int kcp   = (k0 >> 3) & 3;
    int kcl   = kcp ^ ((row >> 1) & 3);
    int klog  = kcell * 32 + kcl * 8;
    int c = row >> 2, ggate = row & 3;
    int zc = ggate * 256 + c;
    int part = (klog >= 2304) ? 1 : 0;
    int rem  = klog - part * 2304;
    int tap  = rem >> 8;
    int ci   = rem & 255;
    const float* src = W + (size_t)zc * 4608 + (size_t)(part * 256 + ci) * 9 + tap;
    _Float16* dst = Wp + (size_t)row * 4608 + k0;
#pragma unroll
    for (int j = 0; j < 8; ++j) dst[j] = (_Float16)src[(size_t)j * 9];
}

// ---------------------------------------------------------------------------
// MFMA implicit-GEMM conv3x3 + BN + ReLU + pool2x2 (blocks 2 and 3).
// 128x64 tile (r16-measured BEST); PAIRED K-steps: one barrier + counted
// vmcnt per 2 steps; 6 LDS buffers (72KB, 2 blocks/CU), cb/ib rotation.
// ---------------------------------------------------------------------------
template <int CI, int OC, int SIN>
__global__ __launch_bounds__(256, 2) void conv_mfma_kernel(
    const _Float16* __restrict__ Wc, const _Float16* __restrict__ in,
    const float* __restrict__ bias, const float* __restrict__ g,
    const float* __restrict__ be, const float* __restrict__ m,
    const float* __restrict__ v, const _Float16* __restrict__ zpage,
    _Float16* __restrict__ out)
{
    constexpr int K    = CI * 9;
    constexpr int KS   = K / 32;
    constexpr int NP   = KS / 2;
    constexpr int SPT  = CI / 32;
    constexpr int NPX  = SIN * SIN;
    constexpr int POOL = SIN / 2;
    constexpr int NPP  = NPX / 4;
    constexpr int NT     = (32 * NPX) / 64;
    constexpr int NCHUNK = NT / 8;

    __shared__ _Float16 Al[6][4096];   // 128 rows x 32 k (8KB each)
    __shared__ _Float16 Bl[6][2048];   // 64 px x 32 k (4KB each)

    const int tid = threadIdx.x;
    const int gx   = blockIdx.x & 7;
    const int rest = blockIdx.x >> 3;
    const int nb   = gx * NCHUNK + (rest % NCHUNK);
    const int bm   = rest / NCHUNK;

    const int n0  = nb * 64;
    const int img = n0 / NPX;
    const int r   = n0 - img * NPX;

    const int srow = tid >> 2;
    const int kc   = tid & 3;
    const int kcs  = kc ^ ((srow >> 1) & 3);
    const int wid  = tid >> 6;

    const _Float16* aptr  = Wc + (size_t)(bm * 128 + srow) * K + kc * 8;
    const _Float16* aptr2 = aptr + (size_t)64 * K;

    const int rn   = r + srow;
    const int ppix = rn >> 2, quad = rn & 3;
    const int y = (ppix / POOL) * 2 + (quad >> 1);
    const int x = (ppix % POOL) * 2 + (quad & 1);
    const _Float16* imgbase = in + (size_t)img * NPX * CI;

    const int lane = tid & 63;
    const int kq   = lane >> 4;
    const int acol = lane & 15;
    int a_off[2], b_off[4];
#pragma unroll
    for (int mf = 0; mf < 2; mf++) {
        int arow = wid * 32 + mf * 16 + acol;
        a_off[mf] = arow * 64 + ((kq ^ ((arow >> 1) & 3)) << 4);
    }
#pragma unroll
    for (int nf = 0; nf < 4; nf++) {
        int brow = nf * 16 + acol;
        b_off[nf] = brow * 64 + ((kq ^ ((brow >> 1) & 3)) << 4);
    }

    f32x4 acc[2][4];
#pragma unroll
    for (int mf = 0; mf < 2; mf++)
#pragma unroll
        for (int nf = 0; nf < 4; nf++) acc[mf][nf] = {0.f, 0.f, 0.f, 0.f};

    // stage K-steps sp, sp+1 (same conv tap) into buffers b2, b2+1
    auto stage_pair = [&](int sp, int b2) {
        gload_lds16(aptr  + (size_t)sp * 32,       (char*)&Al[b2][0]            + wid * 1024);
        gload_lds16(aptr  + (size_t)(sp + 1) * 32, (char*)&Al[b2 + 1][0]        + wid * 1024);
        gload_lds16(aptr2 + (size_t)sp * 32,       (char*)&Al[b2][0]     + 4096 + wid * 1024);
        gload_lds16(aptr2 + (size_t)(sp + 1) * 32, (char*)&Al[b2 + 1][0] + 4096 + wid * 1024);
        int tap = sp / SPT;
        int ci0 = (sp % SPT) * 32;
        int dy = tap / 3 - 1, dx = tap - (tap / 3) * 3 - 1;
        int yy = y + dy, xx = x + dx;
        bool ok = (yy >= 0) && (yy < SIN) && (xx >= 0) && (xx < SIN);
        const _Float16* base = ok ? (imgbase + (size_t)(yy * SIN + xx) * CI) : zpage;
        const _Float16* p0 = base + ci0 + kcs * 8;
        gload_lds16(p0,      (char*)&Bl[b2][0]     + wid * 1024);
        gload_lds16(p0 + 32, (char*)&Bl[b2 + 1][0] + wid * 1024);
    };

    stage_pair(0, 0);
    stage_pair(2, 2);

    int cb = 0, ib = 4;
    for (int p = 0; p < NP; ++p) {
        __builtin_amdgcn_sched_barrier(0);
        if (p < NP - 1) asm volatile("s_waitcnt vmcnt(6)" ::: "memory");
        else            asm volatile("s_waitcnt vmcnt(0)" ::: "memory");
        __builtin_amdgcn_s_barrier();
        int sp = 2 * p + 4;
        if (sp < KS) stage_pair(sp, ib);

#pragma unroll
        for (int hs = 0; hs < 2; ++hs) {
            const int bb = cb + hs;
            half8 af[2], bf[4];
#pragma unroll
            for (int mf = 0; mf < 2; mf++)
                af[mf] = *(const half8*)((const char*)&Al[bb][0] + a_off[mf]);
#pragma unroll
            for (int nf = 0; nf < 4; nf++)
                bf[nf] = *(const half8*)((const char*)&Bl[bb][0] + b_off[nf]);
#pragma unroll
            for (int mf = 0; mf < 2; mf++)
#pragma unroll
                for (int nf = 0; nf < 4; nf++)
                    acc[mf][nf] = __builtin_amdgcn_mfma_f32_16x16x32_f16(
                        af[mf], bf[nf], acc[mf][nf], 0, 0, 0);
        }

        cb = (cb == 4) ? 0 : cb + 2;
        ib = (ib == 4) ? 0 : ib + 2;
    }

#pragma unroll
    for (int mf = 0; mf < 2; mf++) {
        const int oc0w = bm * 128 + wid * 32 + mf * 16 + kq * 4;
        float sc[4], sh[4];
#pragma unroll
        for (int j = 0; j < 4; j++) {
            int oc = oc0w + j;
            sc[j] = g[oc] * rsqrtf(v[oc] + BN_EPS);
            sh[j] = be[oc] - m[oc] * sc[j] + bias[oc] * sc[j];
        }
#pragma unroll
        for (int nf = 0; nf < 4; nf++) {
            f32x4 a = acc[mf][nf];
            half4 hv;
#pragma unroll
            for (int j = 0; j < 4; j++) {
                float val = fmaxf(a[j] * sc[j] + sh[j], 0.f);
                val = fmaxf(val, __shfl_xor(val, 1));
                val = fmaxf(val, __shfl_xor(val, 2));
                hv[j] = (_Float16)val;
            }
            if ((acol & 3) == 0) {
                int pl = (r + nf * 16 + acol) >> 2;
                *(half4*)(&out[((size_t)img * NPP + pl) * OC + oc0w]) = hv;
            }
        }
    }
}

// ---------------------------------------------------------------------------
// Serial-loop kernel (r14-verified BEST config): 64x32 tile, 256 threads =
// 4 waves, PAIRED K-steps, one barrier + vmcnt per 2 steps, 6 LDS buffers
// (36KB -> 4 blocks/CU). Waves 0-1 stage B, waves 2-3 A only. UNCHANGED.
// ---------------------------------------------------------------------------
struct Seg {
    const _Float16* W;       // row base (x-part: Wp; h-part: Wp + 2304)
    const float* lbias;
    const _Float16* hsrc; long hs;   // conv input image [px][ch]
    _Float16* zx;  long zxs;         // gate quads: in (mode 0) / out (mode 1)
    float* cstate;
    _Float16* hdst; long hds;
    float* outseq; long osb;
    float* outlast;
    int mode;
};

__global__ __launch_bounds__(256, 4) void lstm3_kernel(
    Seg s0, Seg s1, Seg s2, Seg s3, int e0, int e1, int e2,
    const _Float16* __restrict__ zpage)
{
    __shared__ _Float16 Al[6][2048];   // 64 rows x 32 k (4KB each)
    __shared__ _Float16 Bl[6][1024];   // 32 px  x 32 k (2KB each)

    const int b = blockIdx.x;
    Seg S; int i;
    if (b < e0)      { S = s0; i = b; }
    else if (b < e1) { S = s1; i = b - e0; }
    else if (b < e2) { S = s2; i = b - e1; }
    else             { S = s3; i = b - e2; }

    const int tid = threadIdx.x;
    const int bm  = (i & 7) | (((i >> 3) & 1) << 3);   // 0..15, low3 XCD-stable
    const int nn  = i >> 4;                            // 0..15
    const int img = nn >> 3;
    const int px0 = (nn & 7) * 32;

    const int wid  = tid >> 6;
    const int lane = tid & 63;
    const int lrow = lane >> 2;           // 0..15
    const int kc   = lane & 3;
    const int rowt = wid * 16 + lrow;     // tile row (A stage) / tile pixel (B, wid<2)
    const int kcs  = kc ^ ((rowt >> 1) & 3);

    const _Float16* aptr = S.W + (size_t)(bm * 64 + rowt) * 4608 + kc * 8;

    const int p_pix = px0 + rowt;         // valid for wid<2 (B staging)
    const int py = p_pix >> 4, px = p_pix & 15;

    const _Float16* srcH = S.hsrc + (size_t)img * S.hs;

    const int kq   = lane >> 4;
    const int acol = lane & 15;
    const int arow = wid * 16 + acol;
    const int a_off  = arow * 64 + ((kq ^ ((arow >> 1) & 3)) << 4);
    const int b_off0 = acol * 64 + ((kq ^ ((acol >> 1) & 3)) << 4);
    const int brow1  = 16 + acol;
    const int b_off1 = brow1 * 64 + ((kq ^ ((brow1 >> 1) & 3)) << 4);

    f32x4 acc0 = {0.f, 0.f, 0.f, 0.f};
    f32x4 acc1 = {0.f, 0.f, 0.f, 0.f};

    const int NPAIR = 36;   // 72 K-steps / 2

    // issue stages s2 and s2+1 (always the same conv tap) into bufs b2, b2+1
    auto stage_pair = [&](int sp, int b2) {
        gload_lds16(aptr + (size_t)sp * 32,       (char*)&Al[b2][0]     + wid * 1024);
        gload_lds16(aptr + (size_t)(sp + 1) * 32, (char*)&Al[b2 + 1][0] + wid * 1024);
        if (wid < 2) {
            int tap = sp >> 3;
            int cc  = sp & 7;
            int t3  = tap / 3;
            int dy = t3 - 1, dx = tap - t3 * 3 - 1;
            int yy = py + dy, xx = px + dx;
            bool ok = (yy >= 0) && (yy < 16) && (xx >= 0) && (xx < 16);
            const _Float16* bsrc = ok ? (srcH + (size_t)(yy * 16 + xx) * 256) : zpage;
            const _Float16* p0 = bsrc + cc * 32 + kcs * 8;
            gload_lds16(p0,      (char*)&Bl[b2][0]     + wid * 1024);
            gload_lds16(p0 + 32, (char*)&Bl[b2 + 1][0] + wid * 1024);
        }
    };

    stage_pair(0, 0);
    stage_pair(2, 2);

    int cb = 0;   // buffer of even consumed step
    int ib = 4;   // buffer of even issued stage
    for (int p = 0; p < NPAIR; ++p) {
        __builtin_amdgcn_sched_barrier(0);
        if (wid < 2) {
            if (p < NPAIR - 1) asm volatile("s_waitcnt vmcnt(4)" ::: "memory");
            else               asm volatile("s_waitcnt vmcnt(0)" ::: "memory");
        } else {
            if (p < NPAIR - 1) asm volatile("s_waitcnt vmcnt(2)" ::: "memory");
            else               asm volatile("s_waitcnt vmcnt(0)" ::: "memory");
        }
        __builtin_amdgcn_s_barrier();
        int sp = 2 * p + 4;
        if (sp < 72) stage_pair(sp, ib);

        // step 2p (buf cb)
        {
            half8 af  = *(const half8*)((const char*)&Al[cb][0] + a_off);
            half8 bf0 = *(const half8*)((const char*)&Bl[cb][0] + b_off0);
            half8 bf1 = *(const half8*)((const char*)&Bl[cb][0] + b_off1);
            acc0 = __builtin_amdgcn_mfma_f32_16x16x32_f16(af, bf0, acc0, 0, 0, 0);
            acc1 = __builtin_amdgcn_mfma_f32_16x16x32_f16(af, bf1, acc1, 0, 0, 0);
        }
        // step 2p+1 (buf cb+1)
        {
            half8 af  = *(const half8*)((const char*)&Al[cb + 1][0] + a_off);
            half8 bf0 = *(const half8*)((const char*)&Bl[cb + 1][0] + b_off0);
            half8 bf1 = *(const half8*)((const char*)&Bl[cb + 1][0] + b_off1);
            acc0 = __builtin_amdgcn_mfma_f32_16x16x32_f16(af, bf0, acc0, 0, 0, 0);
            acc1 = __builtin_amdgcn_mfma_f32_16x16x32_f16(af, bf1, acc1, 0, 0, 0);
        }

        cb = (cb == 4) ? 0 : cb + 2;
        ib = (ib == 4) ? 0 : ib + 2;
    }

    const int c = bm * 16 + wid * 4 + kq;

    if (S.mode == 1) {
        // x-conv GEMM: write gate quads
#pragma unroll
        for (int cN = 0; cN < 2; ++cN) {
            f32x4 a = cN ? acc1 : acc0;
            int pxg = px0 + cN * 16 + acol;
            half4 hv;
#pragma unroll
            for (int j = 0; j < 4; j++) hv[j] = (_Float16)a[j];
            *(half4*)(&S.zx[(size_t)img * S.zxs + ((size_t)c * 256 + pxg) * 4]) = hv;
        }
        return;
    }

    // ---- cell epilogue: z = acc + zx + bias ----
    float bi  = S.lbias[c];
    float bf_ = S.lbias[256 + c];
    float bo  = S.lbias[512 + c];
    float bg  = S.lbias[768 + c];

#pragma unroll
    for (int cN = 0; cN < 2; ++cN) {
        f32x4 a = cN ? acc1 : acc0;
        int pxg = px0 + cN * 16 + acol;
        half4 zv = *(const half4*)(&S.zx[(size_t)img * S.zxs + ((size_t)c * 256 + pxg) * 4]);
        size_t off = (size_t)img * 65536 + (size_t)c * 256 + pxg;
        float zi = a[0] + (float)zv[0] + bi;
        float zf = a[1] + (float)zv[1] + bf_;
        float zo = a[2] + (float)zv[2] + bo;
        float zg = a[3] + (float)zv[3] + bg;
        float cold = S.cstate[off];
        float cn = sigmoidf_(zf) * cold + sigmoidf_(zi) * tanhf_(zg);
        float hn = sigmoidf_(zo) * tanhf_(cn);
        S.cstate[off] = cn;
        S.hdst[(size_t)img * S.hds + (size_t)pxg * 256 + c] = (_Float16)hn;
        if (S.outseq) {
            S.outseq[(size_t)img * S.osb + (size_t)c * 256 + pxg] = hn;
            if (S.outlast)
                S.outlast[(size_t)img * 65536 + (size_t)c * 256 + pxg] = hn;
        }
    }
}

// ---------------------------------------------------------------------------
extern "C" void kernel_launch(void* const* d_in, const int* in_sizes, int n_in,
                              void* d_out, int out_size, void* d_ws, size_t ws_size,
                              hipStream_t stream)
{
    const float* x   = (const float*)d_in[0];
    const float* w0  = (const float*)d_in[1];
    const float* b0  = (const float*)d_in[2];
    const float* g0  = (const float*)d_in[3];
    const float* be0 = (const float*)d_in[4];
    const float* m0  = (const float*)d_in[5];
    const float* v0  = (const float*)d_in[6];
    const float* w1  = (const float*)d_in[7];
    const float* b1  = (const float*)d_in[8];
    const float* g1  = (const float*)d_in[9];
    const float* be1 = (const float*)d_in[10];
    const float* m1  = (const float*)d_in[11];
    const float* v1  = (const float*)d_in[12];
    const float* w2  = (const float*)d_in[13];
    const float* b2  = (const float*)d_in[14];
    const float* g2  = (const float*)d_in[15];
    const float* be2 = (const float*)d_in[16];
    const float* m2  = (const float*)d_in[17];
    const float* v2  = (const float*)d_in[18];
    const float* lw0 = (const float*)d_in[19];
    const float* lb0 = (const float*)d_in[20];
    const float* lw1 = (const float*)d_in[21];
    const float* lb1 = (const float*)d_in[22];

    float* out = (float*)d_out;   // fp32 output

    // ---- workspace layout (bytes), peak ~48.3 MiB ----
    char* base = (char*)d_ws;
    _Float16* Wp0  = (_Float16*)(base);                // [0, 9437184)
    _Float16* Wp1  = (_Float16*)(base + 9437184);      // [9437184, 18874368)
    _Float16* h0s  = (_Float16*)(base + 18874368);     // 4 MiB
    _Float16* y2h  = (_Float16*)(base + 25165824);     // 4 MiB
    _Float16* Wc2  = (_Float16*)(base + 29360128);     // 147,456
    _Float16* Wc3  = (_Float16*)(base + 29507584);     // 589,824
    _Float16* zpg  = (_Float16*)(base + 30097408);     // 131,072
    _Float16* hb1a = (_Float16*)(base + 30228480);     // 262,144
    _Float16* hb1b = (_Float16*)(base + 30490624);     // 262,144
    float*    cst0 = (float*)(base + 30752768);        // 524,288
    float*    cst1 = (float*)(base + 31277056);        // 524,288
    _Float16* zx1a = (_Float16*)(base + 31801344);     // 1,048,576
    _Float16* zx1b = (_Float16*)(base + 32849920);     // 1,048,576
    _Float16* zx0  = (_Float16*)(base + 33898496);     // 16,777,216
    // CNN-phase-only regions (time-disjoint):
    _Float16* y0   = (_Float16*)(base);                // [0, 16777216)
    _Float16* y1   = (_Float16*)(base + 16777216);     // [16777216, 25165824)

    // one memset clears zpg + hb1a/b (written before read) + cst0 + cst1
    hipMemsetAsync(zpg, 0, (size_t)(31801344 - 30097408), stream);

    // ---- CNN encoder ----
    cnn_block1_kernel<1, 64, 128, 8><<<32 * 8 * 16, 256, 0, stream>>>(
        x, w0, b0, g0, be0, m0, v0, y0);
    wprep_conv_kernel<128, 64><<<36, 256, 0, stream>>>(w1, Wc2);
    conv_mfma_kernel<64, 128, 64><<<2048, 256, 0, stream>>>(
        Wc2, y0, b1, g1, be1, m1, v1, zpg, y1);
    wprep_conv_kernel<256, 128><<<144, 256, 0, stream>>>(w2, Wc3);
    conv_mfma_kernel<128, 256, 32><<<1024, 256, 0, stream>>>(
        Wc3, y1, b2, g2, be2, m2, v2, zpg, y2h);

    // ---- LSTM weight prep, both layers in one launch (y0/y1 dead now) ----
    wprep2_kernel<<<4608, 256, 0, stream>>>(lw0, Wp0, lw1, Wp1);

    const long IS = 16 * 65536;

    auto makeD = [&](int t) {
        Seg D{};
        D.W = Wp0; D.lbias = lb0;
        D.hsrc = y2h + (size_t)t * 65536; D.hs = IS;
        D.zx = zx0 + (size_t)t * 262144; D.zxs = 16 * 262144;
        D.cstate = nullptr; D.hdst = nullptr; D.hds = 0;
        D.outseq = nullptr; D.osb = 0; D.outlast = nullptr; D.mode = 1;
        return D;
    };

    // ---- pre-loop: zx0 for t=0,1 (A[0] and A[1] consume them) ----
    {
        Seg D0 = makeD(0), D1 = makeD(1);
        lstm3_kernel<<<512, 256, 0, stream>>>(D0, D1, D1, D1, 256, 512, 512, zpg);
    }

    // ---- serial pipeline: dispatch d = {A:L0[d], C:zx1[d-1], B:L1[d-2], D:zx0[d+2]} ----
    for (int d = 0; d <= 17; ++d) {
        const bool doA = (d <= 15);
        const bool doC = (d >= 1 && d <= 16);
        const bool doB = (d >= 2);
        const bool doD = (d <= 13);

        Seg segs[4]; int ns = 0; int cum = 0; int ends[4];
        if (doA) {
            int t = d;
            Seg A{};
            A.W = Wp0 + 2304; A.lbias = lb0;
            A.hsrc = (t == 0) ? zpg : (h0s + (size_t)(t - 1) * 65536);
            A.hs   = (t == 0) ? 0 : IS;
            A.zx = zx0 + (size_t)t * 262144; A.zxs = 16 * 262144;
            A.cstate = cst0;
            A.hdst = h0s + (size_t)t * 65536; A.hds = IS;
            A.outseq = nullptr; A.osb = 0; A.outlast = nullptr; A.mode = 0;
            segs[ns] = A; cum += 256; ends[ns++] = cum;
        }
        if (doC) {
            int u = d - 1;
            Seg C{};
            C.W = Wp1; C.lbias = lb1;
            C.hsrc = h0s + (size_t)u * 65536; C.hs = IS;
            C.zx = (u & 1) ? zx1b : zx1a; C.zxs = 262144;
            C.cstate = nullptr; C.hdst = nullptr; C.hds = 0;
            C.outseq = nullptr; C.osb = 0; C.outlast = nullptr; C.mode = 1;
            segs[ns] = C; cum += 256; ends[ns++] = cum;
        }
        if (doB) {
            int v = d - 2;
            Seg B{};
            B.W = Wp1 + 2304; B.lbias = lb1;
            B.hsrc = (v == 0) ? zpg : ((v & 1) ? hb1a : hb1b);
            B.hs   = (v == 0) ? 0 : 65536;
            B.zx = (v & 1) ? zx1b : zx1a; B.zxs = 262144;
            B.cstate = cst1;
            B.hdst = (v & 1) ? hb1b : hb1a; B.hds = 65536;
            B.outseq = out + (size_t)v * 65536; B.osb = 1048576;
            B.outlast = (v == 15) ? (out + 2097152) : nullptr; B.mode = 0;
            segs[ns] = B; cum += 256; ends[ns++] = cum;
        }
        if (doD) {
            segs[ns] = makeD(d + 2); cum += 256; ends[ns++] = cum;
        }
        for (int k = ns; k < 4; ++k) segs[k] = segs[0];
        int e0 = ends[0];
        int e1 = (ns > 1) ? ends[1] : cum;
        int e2 = (ns > 2) ? ends[2] : cum;
        lstm3_kernel<<<cum, 256, 0, stream>>>(
            segs[0], segs[1], segs[2], segs[3], e0, e1, e2, zpg);
    }
}